// Round 9
// baseline (66.876 us; speedup 1.0000x reference)
//
#include <hip/hip_runtime.h>

// Maj3 via 4-class reformulation + MFMA (verified R7/R8):
//   clip(w1x1+w2x2+w3x3) = w1 * clip(x1 + (w1w2)x2 + (w1w3)x3),  w in {+-1}
//   y[n, G*4+q] = clip(x1 +- x2 +- x3)   (fp16);  M[a, G*4+q] = w1 or 0
//   out[n,a] = 3 * sum_k y[n,k] * M[k,a]   -> 16x16x32 f16 MFMA, K=768
// R9: occupancy pass. af[24] full prefetch (96 VGPR, forced 2 blocks/CU)
// -> depth-6 rolling ring from L2-hot M32 (24 VGPR), __launch_bounds__(256,4)
// -> 4 blocks/CU, 16 waves/CU (LDS 4x39168 = 156.7KB fits 160KB). Phase
// boundaries + M latency now hidden by TLP instead of register hoarding.

typedef unsigned int u32;
typedef float f4 __attribute__((ext_vector_type(4)));
typedef _Float16 h8 __attribute__((ext_vector_type(8)));
typedef __fp16 hp2 __attribute__((ext_vector_type(2)));
typedef u32 uu2 __attribute__((ext_vector_type(2)));
typedef int i4 __attribute__((ext_vector_type(4)));

#define HS    19            // h-stride (words) in x tile: odd -> no conflicts
#define PLANE (64 * HS)     // 1216 words per w-plane
#define NP    16            // positions per block

__device__ __forceinline__ float clip1(float s) {
    return __builtin_amdgcn_fmed3f(s, -1.0f, 1.0f);
}

// yb index for (G, p): [(G/2)][p][ (G&1)*2 + {0,1} ]  (16B-aligned per (G/2,p))
__device__ __forceinline__ int ybi(int G, int p) {
    return ((G >> 1) * NP + p) * 4 + (G & 1) * 2;
}

// ---- prep: M[a][k=G*4+q] fp16, stored as u32 pairs: M32[a*384 + G*2 + {0,1}]
__global__ __launch_bounds__(192) void prep_kernel(const float* __restrict__ w,
                                                   u32* __restrict__ M32) {
    const int a = blockIdx.x, G = threadIdx.x;
    const float w1 = w[a * 576 + G];
    const float w2 = w[a * 576 + 192 + G];
    const float w3 = w[a * 576 + 384 + G];
    const int q = ((w1 * w2 < 0.f) ? 2 : 0) + ((w1 * w3 < 0.f) ? 1 : 0);
    const u32 s1 = (w1 < 0.f) ? 0xBC00u : 0x3C00u;   // fp16 -1 : +1
    const u32 v0 = (q == 0) ? s1 : 0u, v1 = (q == 1) ? s1 : 0u;
    const u32 v2 = (q == 2) ? s1 : 0u, v3 = (q == 3) ? s1 : 0u;
    M32[a * 384 + G * 2 + 0] = v0 | (v1 << 16);
    M32[a * 384 + G * 2 + 1] = v2 | (v3 << 16);
}

// ---- phase A: 12 consecutive G starting at 9*ci0 + R0 for position-lane p.
// G = 9*ci + r: U-terms at c-offsets {0, 21+(r+3)/9, 42+(r+6)/9}, uv offsets
// {r, (r+3)%9, (r+6)%9} -- all compile-time per d.
template <int R0>
__device__ __forceinline__ void phaseA_12(const float* __restrict__ xt,
                                          u32* __restrict__ yb,
                                          int ci0, int p) {
#pragma unroll
    for (int d = 0; d < 12; ++d) {
        const int r    = (R0 + d) % 9;
        const int cinc = (R0 + d) / 9;              // 0 or 1
        const int uv1 = r;           const int cA = 0;
        const int uv2 = (r + 3) % 9; const int cB = 21 + (r + 3) / 9;
        const int uv3 = (r + 6) % 9; const int cC = 42 + (r + 6) / 9;
        const int ci = ci0 + cinc;
        const float x1 = xt[(uv1 / 3) * PLANE + (ci + cA) * HS + p + (uv1 % 3)];
        const float x2 = xt[(uv2 / 3) * PLANE + (ci + cB) * HS + p + (uv2 % 3)];
        const float x3 = xt[(uv3 / 3) * PLANE + (ci + cC) * HS + p + (uv3 % 3)];
        const float sp = x1 + x2, sm = x1 - x2;
        const float y0 = clip1(sp + x3), y1 = clip1(sp - x3);
        const float y2 = clip1(sm + x3), y3 = clip1(sm - x3);
        hp2 lo = __builtin_amdgcn_cvt_pkrtz(y0, y1);
        hp2 hi = __builtin_amdgcn_cvt_pkrtz(y2, y3);
        uu2 pr;
        pr.x = __builtin_bit_cast(u32, lo);
        pr.y = __builtin_bit_cast(u32, hi);
        const int G = 9 * ci + r;
        *(uu2*)&yb[ybi(G, p)] = pr;                 // ds_write_b64, 8B aligned
    }
}

// ---- main: block = 16 positions (1 w-row, h-half) x all 64 channels -------
__global__ __launch_bounds__(256, 4) void maj3_kernel(
        const float* __restrict__ x, const u32* __restrict__ M32,
        float* __restrict__ out) {
    __shared__ float xt[3 * PLANE];        // 14,592 B : [u:3][c:64][hh:18+pad]
    __shared__ u32  yb[96 * NP * 4];       // 24,576 B : y fp16 [G/2][p][4]

    const int tid   = threadIdx.x;
    const int lane  = tid & 63;
    const int wid   = tid >> 6;
    const int blk   = blockIdx.x;          // 512 = bw*2 + hhalf
    const int hhalf = blk & 1;
    const int bw    = blk >> 1;            // bimg*32 + wrow
    const int bimg  = bw >> 5, wrow = bw & 31;
    const int h0    = hhalf * NP;

    const int p16 = lane & 15, sub = lane >> 4;
    const int a0  = wid * 16;

    // ---- staging loads: burst-issue 14 per thread into regs --------------
    // task i = wid + 4*j covers 0..55 (guard i<54): u = i/18, hh = i%18
    const int c = lane;
    const float* xb = x + (bimg * 32 * 32) * 64 + c;
    float vs[14];
#pragma unroll
    for (int j = 0; j < 14; ++j) {
        const int i = wid + 4 * j;
        const int u = i / 18, hh = i - u * 18;
        const int wx = wrow - 1 + u, hx = h0 - 1 + hh;
        float v = -1.0f;
        if (i < 54 && (unsigned)wx < 32u && (unsigned)hx < 32u)
            v = xb[(wx * 32 + hx) * 64];
        vs[j] = v;
    }

    // ---- staging writes ---------------------------------------------------
#pragma unroll
    for (int j = 0; j < 14; ++j) {
        const int i = wid + 4 * j;
        if (i < 54) {
            const int u = i / 18, hh = i - u * 18;
            xt[u * PLANE + c * HS + hh] = vs[j];
        }
    }
    __syncthreads();

    // ---- phase A: 16 (wave,sub) slots x 12 G x 16 positions ---------------
    {
        const int s = wid * 4 + sub;                 // 0..15
        const int ci0 = (4 * s) / 3;                 // = (12s)/9
        const int sel = s % 3;                       // r0 = 3*sel
        if (sel == 0)      phaseA_12<0>(xt, yb, ci0, p16);
        else if (sel == 1) phaseA_12<3>(xt, yb, ci0, p16);
        else               phaseA_12<6>(xt, yb, ci0, p16);
    }
    __syncthreads();

    // ---- phase B: 24 K-steps of 16x16x32 f16 ------------------------------
    // A-frag: depth-6 rolling ring from L2-hot M32 (ring idx compile-time
    // under full unroll); B-frag: one ds_read_b128 per step.
    {
        const u32* mp = M32 + (a0 + p16) * 384 + sub * 4;
        i4 afr[6];
#pragma unroll
        for (int i = 0; i < 6; ++i)
            afr[i] = *(const i4*)(mp + i * 16);

        f4 acc = {0.f, 0.f, 0.f, 0.f};
#pragma unroll
        for (int st = 0; st < 24; ++st) {
            const i4 a_cur = afr[st % 6];
            if (st + 6 < 24)
                afr[st % 6] = *(const i4*)(mp + (st + 6) * 16);
            // Ga = st*8 + sub*2 -> (Ga>>1) = st*4 + sub; 4 u32 contiguous
            const i4 bi = *(const i4*)&yb[((st * 4 + sub) * NP + p16) * 4];
            acc = __builtin_amdgcn_mfma_f32_16x16x32_f16(
                      __builtin_bit_cast(h8, a_cur),
                      __builtin_bit_cast(h8, bi), acc, 0, 0, 0);
        }

        // C/D: col = lane&15 = position, row = sub*4+reg = channel (verified R7)
        const int n = bw * 32 + h0 + p16;
        float* op = out + n * 64 + a0 + sub * 4;
        f4 o;
#pragma unroll
        for (int r = 0; r < 4; ++r) o[r] = 3.0f * acc[r];
        *(f4*)op = o;
    }
}

extern "C" void kernel_launch(void* const* d_in, const int* in_sizes, int n_in,
                              void* d_out, int out_size, void* d_ws, size_t ws_size,
                              hipStream_t stream) {
    const float* x = (const float*)d_in[0];   // (8,32,32,64) f32
    const float* w = (const float*)d_in[1];   // (64,576) f32, exact +/-1.0
    float* out = (float*)d_out;               // (8,32,32,64) f32
    u32* M32 = (u32*)d_ws;                    // 98,304 B used
    prep_kernel<<<64, 192, 0, stream>>>(w, M32);
    maj3_kernel<<<512, 256, 0, stream>>>(x, M32, out);
}